// Round 13
// baseline (2149.330 us; speedup 1.0000x reference)
//
#include <hip/hip_runtime.h>
#include <hip/hip_bf16.h>
#include <stdint.h>

#define NN 50000
#define NE 800000
#define GRID 1024                  // 4 blocks/CU x 256 CUs (launch_bounds contract)
#define GE 3125                    // edge blocks (NE/256)
#define GX 6250                    // cvt_xb blocks
#define GW 352                     // prep_wt blocks
#define GC 112                     // prep_c blocks (448/4)
#define NB 196                     // scan blocks
#define GG 782                     // gemm row tiles ((NN+63)/64)
#define GA2 12500                  // agg128 vblocks ((NN+3)/4)
#define GA1 6250                   // agg64out vblocks ((NN+7)/8)

typedef unsigned short ushort8 __attribute__((ext_vector_type(8)));
typedef __bf16 bf16x8 __attribute__((ext_vector_type(8)));
typedef float f32x4 __attribute__((ext_vector_type(4)));

// ---------- dtype helpers ----------
__device__ __forceinline__ float bf2f_bits(unsigned short u) {
  unsigned int x = ((unsigned int)u) << 16;
  float f;
  __builtin_memcpy(&f, &x, 4);
  return f;
}
__device__ __forceinline__ unsigned short f2bf_bits(float f) {
  unsigned int x;
  __builtin_memcpy(&x, &f, 4);
  unsigned int lsb = (x >> 16) & 1u;
  x += 0x7fffu + lsb;                       // round to nearest even
  return (unsigned short)(x >> 16);
}
__device__ __forceinline__ float lo16(unsigned int v) { return bf2f_bits((unsigned short)v); }
__device__ __forceinline__ float hi16(unsigned int v) { return bf2f_bits((unsigned short)(v >> 16)); }
__device__ __forceinline__ float loadf(const void* base, size_t idx, int isbf) {
  if (isbf) return bf2f_bits(((const unsigned short*)base)[idx]);
  return ((const float*)base)[idx];
}

// ---------- launch 1: dtype sniff + cnt8 zero + barrier-state zero ----------
__global__ void k_sniff(const void* x, const void* ei, int* flags, int* cnt8,
                        int* bar) {
  int i = blockIdx.x * 256 + threadIdx.x;
  if (i < 8 * NN) cnt8[i] = 0;
  if (blockIdx.x != 0) return;
  if (threadIdx.x == 0) { bar[0] = 0; bar[1] = 0; }   // count, generation
  __shared__ int badbf;
  __shared__ int zodd;
  int tid = threadIdx.x;
  if (tid == 0) { badbf = 0; zodd = 0; }
  __syncthreads();
  unsigned short u = ((const unsigned short*)x)[tid];
  float v = bf2f_bits(u);
  float av = fabsf(v);
  int ok = (av == 0.0f) || (av > 1e-8f && av < 1e8f);
  if (!ok) atomicAdd(&badbf, 1);
  int e32 = ((const int*)ei)[tid];
  if ((tid & 1) && e32 == 0) atomicAdd(&zodd, 1);
  __syncthreads();
  if (tid == 0) {
    flags[0] = (badbf <= 12) ? 1 : 0;
    flags[1] = (zodd >= 100) ? 1 : 0;
  }
}

// ---------- mega-kernel args ----------
struct MegaArgs {
  const void* ei; const void* x;
  unsigned short* xb;
  int* rank; int* cnt8; int* indptr; int* bsum;
  float* dinv; int* srcs;
  const void *W1, *Wc0, *Wc1, *Wout;
  const void *g1, *g2, *g3, *g4;
  const void *nb1, *nb2, *nb3, *nb4;      // BN beta
  const void *rm1, *rm2, *rm3, *rm4;
  const void *rv1, *rv2, *rv3, *rv4;
  const void *cb1, *cbc0, *cbc1, *cbout;  // conv biases
  unsigned short* Wtb; float* cvec;
  unsigned short* hb;
  unsigned short *rb0, *rb1, *rb2;
  void* dout;
  int* flags;
  int* bar;                               // [0]=count [1]=generation
};

// ---------- device-scope grid barrier (sense = generation counter) ----------
// All GRID blocks co-resident (launch_bounds(256,4): VGPR<=128, LDS ~2KB ->
// 4 blocks/CU x 256 CUs). atomicAdd on global = device scope [m20];
// __threadfence gives release/acquire across XCD L2s.
__device__ __forceinline__ void gsync(int* bar, int mygen) {
  __syncthreads();
  if (threadIdx.x == 0) {
    __threadfence();
    if (atomicAdd(&bar[0], 1) == GRID - 1) {
      atomicExch(&bar[0], 0);
      __threadfence();
      atomicAdd(&bar[1], 1);
    } else {
      while (atomicAdd(&bar[1], 0) < mygen) __builtin_amdgcn_s_sleep(2);
    }
  }
  __syncthreads();
  __threadfence();                        // acquire: no stale L1 after barrier
}

// ---------- phase bodies ----------
// P0: edge cvt+XCD-sharded count | x->bf16 | W-prep | c-prep
__device__ void prep_body(int bid, const MegaArgs& a) {
  int tid = threadIdx.x;
  if (bid < GE) {
    int e = bid * 256 + tid;
    if (e >= NE) return;
    unsigned int xcc;
    asm volatile("s_getreg_b32 %0, hwreg(HW_REG_XCC_ID)" : "=s"(xcc));
    xcc &= 7;
    int c;
    if (a.flags[1]) c = (int)((const long long*)a.ei)[NE + e];
    else            c = ((const int*)a.ei)[NE + e];
    int rl = atomicAdd(&a.cnt8[xcc * NN + c], 1);
    a.rank[e] = rl | (int)(xcc << 27);
    return;
  }
  bid -= GE;
  if (bid < GX) {
    if (a.flags[0]) return;
    int i4 = (bid * 256 + tid) * 4;
    if (i4 >= NN * 128) return;
    float4 v = *reinterpret_cast<const float4*>((const float*)a.x + i4);
    a.xb[i4 + 0] = f2bf_bits(v.x); a.xb[i4 + 1] = f2bf_bits(v.y);
    a.xb[i4 + 2] = f2bf_bits(v.z); a.xb[i4 + 3] = f2bf_bits(v.w);
    return;
  }
  bid -= GX;
  int isbf = a.flags[0];
  if (bid < GW) {
    int idx = bid * 256 + tid;
    if (idx >= 90112) return;
    const void *W, *g, *rv;
    int K, NOUT, base;
    if (idx < 16384)      { W = a.W1;   g = a.g1; rv = a.rv1; K = 128; NOUT = 128; base = 0; }
    else if (idx < 32768) { W = a.Wc0;  g = a.g2; rv = a.rv2; K = 128; NOUT = 128; base = 16384; }
    else if (idx < 65536) { W = a.Wc1;  g = a.g3; rv = a.rv3; K = 256; NOUT = 128; base = 32768; }
    else                  { W = a.Wout; g = a.g4; rv = a.rv4; K = 384; NOUT = 64;  base = 65536; }
    int li = idx - base;
    int j = li / K, k = li % K;
    float s = loadf(g, k, isbf) * rsqrtf(loadf(rv, k, isbf) + 1e-5f);
    a.Wtb[idx] = f2bf_bits(s * loadf(W, (size_t)k * NOUT + j, isbf));
    return;
  }
  bid -= GW;
  {
    int jj = bid * 4 + (tid >> 6);
    int lane = tid & 63;
    if (jj >= 448) return;
    const void *W, *g, *bb, *rm, *rv;
    int K, NOUT, j;
    if (jj < 128)      { W = a.W1;   g = a.g1; bb = a.nb1; rm = a.rm1; rv = a.rv1; K = 128; NOUT = 128; j = jj; }
    else if (jj < 256) { W = a.Wc0;  g = a.g2; bb = a.nb2; rm = a.rm2; rv = a.rv2; K = 128; NOUT = 128; j = jj - 128; }
    else if (jj < 384) { W = a.Wc1;  g = a.g3; bb = a.nb3; rm = a.rm3; rv = a.rv3; K = 256; NOUT = 128; j = jj - 256; }
    else               { W = a.Wout; g = a.g4; bb = a.nb4; rm = a.rm4; rv = a.rv4; K = 384; NOUT = 64;  j = jj - 384; }
    float acc = 0.f;
    for (int k = lane; k < K; k += 64) {
      float s = loadf(g, k, isbf) * rsqrtf(loadf(rv, k, isbf) + 1e-5f);
      float t = loadf(bb, k, isbf) - loadf(rm, k, isbf) * s;
      acc += t * loadf(W, (size_t)k * NOUT + j, isbf);
    }
#pragma unroll
    for (int off = 32; off; off >>= 1) acc += __shfl_down(acc, off);
    if (lane == 0) a.cvec[jj] = acc;
  }
}

// P1: shard offsets in place + block totals + dinv
__device__ void scan1_body(int b, const MegaArgs& a) {
  __shared__ int sm1[256];
  int tid = threadIdx.x;
  int i = b * 256 + tid;
  int v = 0;
  if (i < NN) {
    int run = 0;
#pragma unroll
    for (int s = 0; s < 8; ++s) {
      int cs = a.cnt8[s * NN + i];
      a.cnt8[s * NN + i] = run;        // exclusive shard offset
      run += cs;
    }
    v = run;
    a.dinv[i] = rsqrtf((float)(v + 1));   // +1 self loop
  }
  sm1[tid] = v;
  __syncthreads();
  for (int off = 1; off < 256; off <<= 1) {
    int t = (tid >= off) ? sm1[tid - off] : 0;
    __syncthreads();
    sm1[tid] += t;
    __syncthreads();
  }
  if (i < NN) a.indptr[i] = sm1[tid] - v;
  if (tid == 255) a.bsum[b] = sm1[255];
  __syncthreads();
}

// P2: per-block redundant prefix of bsum + apply
__device__ void scan23_body(int b, const MegaArgs& a) {
  __shared__ int sm2[256];
  int tid = threadIdx.x;
  sm2[tid] = (tid < NB && tid < b) ? a.bsum[tid] : 0;
  __syncthreads();
  for (int off = 128; off; off >>= 1) {
    if (tid < off) sm2[tid] += sm2[tid + off];
    __syncthreads();
  }
  int S = sm2[0];
  int i = b * 256 + tid;
  if (i < NN) a.indptr[i] += S;
  else if (i == NN) a.indptr[NN] = NE;
  __syncthreads();
}

// GEMM body (64 rows/block, 4 waves, direct-from-global A, MFMA)
template <int NOUT, int K>
__device__ void gemm_body(
    int bid,
    const unsigned short* __restrict__ h0, const unsigned short* __restrict__ h1,
    const unsigned short* __restrict__ h2,
    const unsigned short* __restrict__ Wtb,
    const float* __restrict__ cvec, const float* __restrict__ dinv,
    unsigned short* __restrict__ hb) {
  constexpr int KS = K / 32;
  constexpr int NT = NOUT / 16;
  int tid = threadIdx.x;
  int wv = tid >> 6, lane = tid & 63;
  int row0 = bid * 64 + wv * 16;
  int l15 = lane & 15;
  int kq = lane >> 4;
  int arow = row0 + l15;
  bool inb = arow < NN;

  bf16x8 afrag[KS];
#pragma unroll
  for (int ks = 0; ks < KS; ++ks) {
    int kg = ks * 32 + kq * 8;
    const unsigned short* src = (kg >> 7) == 0 ? h0 : ((kg >> 7) == 1 ? h1 : h2);
    ushort8 u = (ushort8)0;
    if (inb) u = *reinterpret_cast<const ushort8*>(src + (size_t)arow * 128 + (kg & 127));
    afrag[ks] = __builtin_bit_cast(bf16x8, u);
  }
  f32x4 acc[NT];
#pragma unroll
  for (int nt = 0; nt < NT; ++nt) acc[nt] = (f32x4)0.f;
#pragma unroll
  for (int nt = 0; nt < NT; ++nt) {
    const unsigned short* wrow = Wtb + (size_t)(nt * 16 + l15) * K + kq * 8;
#pragma unroll
    for (int ks = 0; ks < KS; ++ks) {
      ushort8 u = *reinterpret_cast<const ushort8*>(wrow + ks * 32);
      acc[nt] = __builtin_amdgcn_mfma_f32_16x16x32_bf16(
          afrag[ks], __builtin_bit_cast(bf16x8, u), acc[nt], 0, 0, 0);
    }
  }
  int orow0 = row0 + kq * 4;
  float dv[4];
  bool ob[4];
#pragma unroll
  for (int r = 0; r < 4; ++r) {
    int orow = orow0 + r;
    ob[r] = orow < NN;
    dv[r] = ob[r] ? dinv[orow] : 0.f;
  }
#pragma unroll
  for (int nt = 0; nt < NT; ++nt) {
    int col = nt * 16 + l15;
    float cv = cvec[col];
#pragma unroll
    for (int r = 0; r < 4; ++r) {
      if (ob[r])
        hb[(size_t)(orow0 + r) * NOUT + col] = f2bf_bits(dv[r] * (acc[nt][r] + cv));
    }
  }
}

// P3: atomic-free scatter fill (re-decodes edges) || GEMM L1
__device__ void fillgemm1_body(int bid, const MegaArgs& a) {
  if (bid < GE) {
    int e = bid * 256 + threadIdx.x;
    if (e >= NE) return;
    int r, c;
    if (a.flags[1]) {
      const long long* p = (const long long*)a.ei;
      r = (int)p[e];
      c = (int)p[NE + e];
    } else {
      const int* p = (const int*)a.ei;
      r = p[e];
      c = p[NE + e];
    }
    int rk = a.rank[e];
    int sh = (unsigned int)rk >> 27;
    a.srcs[a.indptr[c] + a.cnt8[sh * NN + c] + (rk & 0x07FFFFFF)] = r;
    return;
  }
  const unsigned short* h0 = a.flags[0] ? (const unsigned short*)a.x : a.xb;
  gemm_body<128, 128>(bid - GE, h0, nullptr, nullptr, a.Wtb, a.cvec, a.dinv, a.hb);
}

// agg128: one wave per node, 8 rows in flight (R8 layout, measured best)
template <bool RELU>
__device__ void agg128_body(int vb, const MegaArgs& a, const void* bias,
                            size_t region_off, unsigned short* rb) {
  int gw = __builtin_amdgcn_readfirstlane(vb * 4 + (threadIdx.x >> 6));
  int lane = threadIdx.x & 63;
  if (gw >= NN) return;
  int isbf = a.flags[0];
  const unsigned short* hb = a.hb;
  int e0 = a.indptr[gw], e1 = a.indptr[gw + 1];
  size_t co = (size_t)lane * 2;
  unsigned int sv = *reinterpret_cast<const unsigned int*>(hb + (size_t)gw * 128 + co);
  float a0 = lo16(sv), a1 = hi16(sv);
  float b0 = 0.f, b1 = 0.f, c0 = 0.f, c1 = 0.f, d0 = 0.f, d1 = 0.f;
  int e = e0;
  const int* srcs = a.srcs;
  for (; e + 7 < e1; e += 8) {
    int s0 = srcs[e], s1 = srcs[e + 1], s2 = srcs[e + 2], s3 = srcs[e + 3];
    int s4 = srcs[e + 4], s5 = srcs[e + 5], s6 = srcs[e + 6], s7 = srcs[e + 7];
    unsigned int v0 = *reinterpret_cast<const unsigned int*>(hb + (size_t)s0 * 128 + co);
    unsigned int v1 = *reinterpret_cast<const unsigned int*>(hb + (size_t)s1 * 128 + co);
    unsigned int v2 = *reinterpret_cast<const unsigned int*>(hb + (size_t)s2 * 128 + co);
    unsigned int v3 = *reinterpret_cast<const unsigned int*>(hb + (size_t)s3 * 128 + co);
    unsigned int v4 = *reinterpret_cast<const unsigned int*>(hb + (size_t)s4 * 128 + co);
    unsigned int v5 = *reinterpret_cast<const unsigned int*>(hb + (size_t)s5 * 128 + co);
    unsigned int v6 = *reinterpret_cast<const unsigned int*>(hb + (size_t)s6 * 128 + co);
    unsigned int v7 = *reinterpret_cast<const unsigned int*>(hb + (size_t)s7 * 128 + co);
    a0 += lo16(v0); a1 += hi16(v0); b0 += lo16(v1); b1 += hi16(v1);
    c0 += lo16(v2); c1 += hi16(v2); d0 += lo16(v3); d1 += hi16(v3);
    a0 += lo16(v4); a1 += hi16(v4); b0 += lo16(v5); b1 += hi16(v5);
    c0 += lo16(v6); c1 += hi16(v6); d0 += lo16(v7); d1 += hi16(v7);
  }
  for (; e < e1; ++e) {
    int s0 = srcs[e];
    unsigned int v0 = *reinterpret_cast<const unsigned int*>(hb + (size_t)s0 * 128 + co);
    a0 += lo16(v0); a1 += hi16(v0);
  }
  float dv = a.dinv[gw];
  float o0 = dv * ((a0 + b0) + (c0 + d0)) + loadf(bias, co + 0, isbf);
  float o1 = dv * ((a1 + b1) + (c1 + d1)) + loadf(bias, co + 1, isbf);
  if (RELU) { o0 = fmaxf(o0, 0.f); o1 = fmaxf(o1, 0.f); }
  size_t eo = region_off + (size_t)gw * 128 + co;
  if (isbf) {
    unsigned int pk = (unsigned int)f2bf_bits(o0) | ((unsigned int)f2bf_bits(o1) << 16);
    *reinterpret_cast<unsigned int*>((unsigned short*)a.dout + eo) = pk;
  } else {
    float2 fo; fo.x = o0; fo.y = o1;
    *reinterpret_cast<float2*>((float*)a.dout + eo) = fo;
    unsigned int pk = (unsigned int)f2bf_bits(o0) | ((unsigned int)f2bf_bits(o1) << 16);
    *reinterpret_cast<unsigned int*>(rb + (size_t)gw * 128 + co) = pk;
  }
}

// agg64out: 32 lanes/node, final layer
__device__ void agg64_body(int vb, const MegaArgs& a) {
  int gw = vb * 8 + (threadIdx.x >> 5);
  int lane = threadIdx.x & 31;
  if (gw >= NN) return;
  int isbf = a.flags[0];
  const unsigned short* hb = a.hb;
  int e0 = a.indptr[gw], e1 = a.indptr[gw + 1];
  int e = e0;
  size_t co = (size_t)lane * 2;
  unsigned int sv = *reinterpret_cast<const unsigned int*>(hb + (size_t)gw * 64 + co);
  float a0 = lo16(sv), a1 = hi16(sv);
  float b0 = 0.f, b1 = 0.f, c0 = 0.f, c1 = 0.f, d0 = 0.f, d1 = 0.f;
  const int* srcs = a.srcs;
  for (; e + 3 < e1; e += 4) {
    int sa = srcs[e], sb = srcs[e + 1], sc = srcs[e + 2], sd = srcs[e + 3];
    unsigned int va = *reinterpret_cast<const unsigned int*>(hb + (size_t)sa * 64 + co);
    unsigned int vb2 = *reinterpret_cast<const unsigned int*>(hb + (size_t)sb * 64 + co);
    unsigned int vc = *reinterpret_cast<const unsigned int*>(hb + (size_t)sc * 64 + co);
    unsigned int vd = *reinterpret_cast<const unsigned int*>(hb + (size_t)sd * 64 + co);
    a0 += lo16(va); a1 += hi16(va); b0 += lo16(vb2); b1 += hi16(vb2);
    c0 += lo16(vc); c1 += hi16(vc); d0 += lo16(vd); d1 += hi16(vd);
  }
  for (; e < e1; ++e) {
    int sa = srcs[e];
    unsigned int va = *reinterpret_cast<const unsigned int*>(hb + (size_t)sa * 64 + co);
    a0 += lo16(va); a1 += hi16(va);
  }
  float dv = a.dinv[gw];
  float o0 = dv * ((a0 + b0) + (c0 + d0)) + loadf(a.cbout, co + 0, isbf);
  float o1 = dv * ((a1 + b1) + (c1 + d1)) + loadf(a.cbout, co + 1, isbf);
  size_t eo = (size_t)gw * 64 + co;
  if (isbf) {
    unsigned int pk = (unsigned int)f2bf_bits(o0) | ((unsigned int)f2bf_bits(o1) << 16);
    *reinterpret_cast<unsigned int*>((unsigned short*)a.dout + eo) = pk;
  } else {
    float2 fo; fo.x = o0; fo.y = o1;
    *reinterpret_cast<float2*>((float*)a.dout + eo) = fo;
  }
}

// ---------- launch 2: persistent mega-kernel, 11 phases / 10 grid barriers ----
__global__ __launch_bounds__(256, 4) void k_mega(MegaArgs a) {
  const size_t offR0 = (size_t)NN * 64;
  const size_t offR1 = offR0 + (size_t)NN * 128;
  const size_t offR2 = offR1 + (size_t)NN * 128;
  unsigned short* d0 = (unsigned short*)a.dout;
  int gen = 0;

  for (int vb = blockIdx.x; vb < GE + GX + GW + GC; vb += GRID) prep_body(vb, a);
  gsync(a.bar, ++gen);
  for (int vb = blockIdx.x; vb < NB; vb += GRID) scan1_body(vb, a);
  gsync(a.bar, ++gen);
  for (int vb = blockIdx.x; vb < NB; vb += GRID) scan23_body(vb, a);
  gsync(a.bar, ++gen);
  for (int vb = blockIdx.x; vb < GE + GG; vb += GRID) fillgemm1_body(vb, a);
  gsync(a.bar, ++gen);
  for (int vb = blockIdx.x; vb < GA2; vb += GRID) agg128_body<true>(vb, a, a.cb1, offR0, a.rb0);
  gsync(a.bar, ++gen);
  {
    int isbf = a.flags[0];
    const unsigned short* h0 = isbf ? d0 + offR0 : a.rb0;
    for (int vb = blockIdx.x; vb < GG; vb += GRID)
      gemm_body<128, 128>(vb, h0, nullptr, nullptr, a.Wtb + 16384, a.cvec + 128, a.dinv, a.hb);
  }
  gsync(a.bar, ++gen);
  for (int vb = blockIdx.x; vb < GA2; vb += GRID) agg128_body<true>(vb, a, a.cbc0, offR1, a.rb1);
  gsync(a.bar, ++gen);
  {
    int isbf = a.flags[0];
    const unsigned short* h0 = isbf ? d0 + offR0 : a.rb0;
    const unsigned short* h1 = isbf ? d0 + offR1 : a.rb1;
    for (int vb = blockIdx.x; vb < GG; vb += GRID)
      gemm_body<128, 256>(vb, h0, h1, nullptr, a.Wtb + 32768, a.cvec + 256, a.dinv, a.hb);
  }
  gsync(a.bar, ++gen);
  for (int vb = blockIdx.x; vb < GA2; vb += GRID) agg128_body<true>(vb, a, a.cbc1, offR2, a.rb2);
  gsync(a.bar, ++gen);
  {
    int isbf = a.flags[0];
    const unsigned short* h0 = isbf ? d0 + offR0 : a.rb0;
    const unsigned short* h1 = isbf ? d0 + offR1 : a.rb1;
    const unsigned short* h2 = isbf ? d0 + offR2 : a.rb2;
    for (int vb = blockIdx.x; vb < GG; vb += GRID)
      gemm_body<64, 384>(vb, h0, h1, h2, a.Wtb + 65536, a.cvec + 384, a.dinv, a.hb);
  }
  gsync(a.bar, ++gen);
  for (int vb = blockIdx.x; vb < GA1; vb += GRID) agg64_body(vb, a);
}

extern "C" void kernel_launch(void* const* d_in, const int* in_sizes, int n_in,
                              void* d_out, int out_size, void* d_ws, size_t ws_size,
                              hipStream_t stream) {
  (void)in_sizes; (void)n_in; (void)out_size; (void)ws_size;
  char* w = (char*)d_ws;
  auto carve = [&](size_t bytes) {
    char* p = w;
    w += (bytes + 255) & ~(size_t)255;
    return p;
  };
  int*   flags  = (int*)  carve(256);
  int*   bar    = (int*)  carve(256);
  float* dinv   = (float*)carve(sizeof(float) * NN);
  int*   cnt8   = (int*)  carve(sizeof(int) * 8 * NN);
  int*   indptr = (int*)  carve(sizeof(int) * (NN + 1));
  int*   bsum   = (int*)  carve(sizeof(int) * 256);
  int*   rank   = (int*)  carve(sizeof(int) * NE);
  int*   srcs   = (int*)  carve(sizeof(int) * NE);
  unsigned short* Wtb = (unsigned short*)carve(sizeof(short) * 90112);
  float* cvec   = (float*)carve(sizeof(float) * 448);
  unsigned short* xb  = (unsigned short*)carve(sizeof(short) * (size_t)NN * 128);
  unsigned short* hb  = (unsigned short*)carve(sizeof(short) * (size_t)NN * 128);
  unsigned short* rb0 = (unsigned short*)carve(sizeof(short) * (size_t)NN * 128);
  unsigned short* rb1 = (unsigned short*)carve(sizeof(short) * (size_t)NN * 128);
  unsigned short* rb2 = (unsigned short*)carve(sizeof(short) * (size_t)NN * 128);

  MegaArgs a;
  a.ei = d_in[1]; a.x = d_in[0];
  a.xb = xb; a.rank = rank; a.cnt8 = cnt8; a.indptr = indptr; a.bsum = bsum;
  a.dinv = dinv; a.srcs = srcs;
  a.W1 = d_in[4]; a.Wc0 = d_in[6]; a.Wc1 = d_in[8]; a.Wout = d_in[10];
  a.cb1 = d_in[5]; a.cbc0 = d_in[7]; a.cbc1 = d_in[9]; a.cbout = d_in[11];
  a.g1 = d_in[12]; a.nb1 = d_in[13]; a.rm1 = d_in[14]; a.rv1 = d_in[15];
  a.g2 = d_in[16]; a.nb2 = d_in[17]; a.rm2 = d_in[18]; a.rv2 = d_in[19];
  a.g3 = d_in[20]; a.nb3 = d_in[21]; a.rm3 = d_in[22]; a.rv3 = d_in[23];
  a.g4 = d_in[24]; a.nb4 = d_in[25]; a.rm4 = d_in[26]; a.rv4 = d_in[27];
  a.Wtb = Wtb; a.cvec = cvec; a.hb = hb;
  a.rb0 = rb0; a.rb1 = rb1; a.rb2 = rb2;
  a.dout = d_out; a.flags = flags; a.bar = bar;

  const int gN8 = (8 * NN + 255) / 256;
  k_sniff<<<gN8, 256, 0, stream>>>(a.x, a.ei, flags, cnt8, bar);
  k_mega<<<GRID, 256, 0, stream>>>(a);
}

// Round 14
// 316.397 us; speedup vs baseline: 6.7932x; 6.7932x over previous
//
#include <hip/hip_runtime.h>
#include <hip/hip_bf16.h>
#include <stdint.h>

#define NN 50000
#define NE 800000
#define GE 3125                    // edge blocks (NE/256)
#define GX 6250                    // cvt_xb blocks (NN*128/4/256)
#define GW 352                     // prep_wt blocks (90112/256)
#define GC 112                     // prep_c blocks (448 cols / 4 per block)
#define NB 196                     // scan blocks ((NN+255)/256)

typedef unsigned short ushort8 __attribute__((ext_vector_type(8)));
typedef __bf16 bf16x8 __attribute__((ext_vector_type(8)));
typedef float f32x4 __attribute__((ext_vector_type(4)));

// ---------- dtype helpers ----------
__device__ __forceinline__ float bf2f_bits(unsigned short u) {
  unsigned int x = ((unsigned int)u) << 16;
  float f;
  __builtin_memcpy(&f, &x, 4);
  return f;
}
__device__ __forceinline__ unsigned short f2bf_bits(float f) {
  unsigned int x;
  __builtin_memcpy(&x, &f, 4);
  unsigned int lsb = (x >> 16) & 1u;
  x += 0x7fffu + lsb;                       // round to nearest even
  return (unsigned short)(x >> 16);
}
__device__ __forceinline__ float lo16(unsigned int v) { return bf2f_bits((unsigned short)v); }
__device__ __forceinline__ float hi16(unsigned int v) { return bf2f_bits((unsigned short)(v >> 16)); }
__device__ __forceinline__ float loadf(const void* base, size_t idx, int isbf) {
  if (isbf) return bf2f_bits(((const unsigned short*)base)[idx]);
  return ((const float*)base)[idx];
}

// ---------- launch 1: dtype sniff (block 0) + cnt8 zeroing ----------
__global__ void k_sniff(const void* x, const void* ei, int* flags, int* cnt8) {
  int i = blockIdx.x * 256 + threadIdx.x;
  if (i < 8 * NN) cnt8[i] = 0;
  if (blockIdx.x != 0) return;
  __shared__ int badbf;
  __shared__ int zodd;
  int tid = threadIdx.x;
  if (tid == 0) { badbf = 0; zodd = 0; }
  __syncthreads();
  unsigned short u = ((const unsigned short*)x)[tid];
  float v = bf2f_bits(u);
  float av = fabsf(v);
  int ok = (av == 0.0f) || (av > 1e-8f && av < 1e8f);
  if (!ok) atomicAdd(&badbf, 1);
  int e32 = ((const int*)ei)[tid];
  if ((tid & 1) && e32 == 0) atomicAdd(&zodd, 1);
  __syncthreads();
  if (tid == 0) {
    flags[0] = (badbf <= 12) ? 1 : 0;
    flags[1] = (zodd >= 100) ? 1 : 0;
  }
}

// ---------- launch 2: cvt_edges || cvt_xb || prep_wt || prep_c (all flag-dep only) ----------
// XCD-sharded degree count (HW_REG_XCC_ID, learn_hip m09): shard counter lines
// stay in one XCD's L2; shard id in rank high bits -> mapping-independent.
__global__ __launch_bounds__(256) void k_fuse_prep(
    const void* ei, const void* x, unsigned short* xb, int* rank, int* cnt8,
    const void* W1, const void* Wc0, const void* Wc1, const void* Wout,
    const void* g1, const void* g2, const void* g3, const void* g4,
    const void* b1, const void* b2, const void* b3, const void* b4,
    const void* rm1, const void* rm2, const void* rm3, const void* rm4,
    const void* rv1, const void* rv2, const void* rv3, const void* rv4,
    unsigned short* Wtb, float* cvec, const int* flags) {
  int bid = blockIdx.x;
  int tid = threadIdx.x;
  if (bid < GE) {                       // --- edge convert + sharded count ---
    int e = bid * 256 + tid;
    if (e >= NE) return;
    unsigned int xcc;
    asm volatile("s_getreg_b32 %0, hwreg(HW_REG_XCC_ID)" : "=s"(xcc));
    xcc &= 7;
    int c;
    if (flags[1]) c = (int)((const long long*)ei)[NE + e];
    else          c = ((const int*)ei)[NE + e];
    int rl = atomicAdd(&cnt8[xcc * NN + c], 1);
    rank[e] = rl | (int)(xcc << 27);
    return;
  }
  bid -= GE;
  if (bid < GX) {                       // --- x -> bf16 (fp32 path only) ---
    if (flags[0]) return;
    int i4 = (bid * 256 + tid) * 4;
    if (i4 >= NN * 128) return;
    float4 v = *reinterpret_cast<const float4*>((const float*)x + i4);
    xb[i4 + 0] = f2bf_bits(v.x); xb[i4 + 1] = f2bf_bits(v.y);
    xb[i4 + 2] = f2bf_bits(v.z); xb[i4 + 3] = f2bf_bits(v.w);
    return;
  }
  bid -= GX;
  int isbf = flags[0];
  if (bid < GW) {                       // --- W' transpose bf16 ---
    int idx = bid * 256 + tid;
    if (idx >= 90112) return;
    const void *W, *g, *rv;
    int K, NOUT, base;
    if (idx < 16384)      { W = W1;   g = g1; rv = rv1; K = 128; NOUT = 128; base = 0; }
    else if (idx < 32768) { W = Wc0;  g = g2; rv = rv2; K = 128; NOUT = 128; base = 16384; }
    else if (idx < 65536) { W = Wc1;  g = g3; rv = rv3; K = 256; NOUT = 128; base = 32768; }
    else                  { W = Wout; g = g4; rv = rv4; K = 384; NOUT = 64;  base = 65536; }
    int li = idx - base;
    int j = li / K, k = li % K;
    float s = loadf(g, k, isbf) * rsqrtf(loadf(rv, k, isbf) + 1e-5f);
    Wtb[idx] = f2bf_bits(s * loadf(W, (size_t)k * NOUT + j, isbf));
    return;
  }
  bid -= GW;
  {                                     // --- cvec: 4 cols/block, 1 per wave ---
    int jj = bid * 4 + (tid >> 6);
    int lane = tid & 63;
    if (jj >= 448) return;
    const void *W, *g, *bb, *rm, *rv;
    int K, NOUT, j;
    if (jj < 128)      { W = W1;   g = g1; bb = b1; rm = rm1; rv = rv1; K = 128; NOUT = 128; j = jj; }
    else if (jj < 256) { W = Wc0;  g = g2; bb = b2; rm = rm2; rv = rv2; K = 128; NOUT = 128; j = jj - 128; }
    else if (jj < 384) { W = Wc1;  g = g3; bb = b3; rm = rm3; rv = rv3; K = 256; NOUT = 128; j = jj - 256; }
    else               { W = Wout; g = g4; bb = b4; rm = rm4; rv = rv4; K = 384; NOUT = 64;  j = jj - 384; }
    float acc = 0.f;
    for (int k = lane; k < K; k += 64) {
      float s = loadf(g, k, isbf) * rsqrtf(loadf(rv, k, isbf) + 1e-5f);
      float t = loadf(bb, k, isbf) - loadf(rm, k, isbf) * s;
      acc += t * loadf(W, (size_t)k * NOUT + j, isbf);
    }
#pragma unroll
    for (int off = 32; off; off >>= 1) acc += __shfl_down(acc, off);
    if (lane == 0) cvec[jj] = acc;
  }
}

// ---------- launch 3: scan1 (shard offsets in place + block totals + dinv) ----------
__global__ void k_scan1(int* cnt8, int* indptr, int* bsum, float* dinv, int n) {
  __shared__ int sm[256];
  int tid = threadIdx.x;
  int i = blockIdx.x * 256 + tid;
  int v = 0;
  if (i < n) {
    int run = 0;
#pragma unroll
    for (int s = 0; s < 8; ++s) {
      int cs = cnt8[s * NN + i];
      cnt8[s * NN + i] = run;        // exclusive shard offset
      run += cs;
    }
    v = run;
    dinv[i] = rsqrtf((float)(v + 1));   // +1 self loop
  }
  sm[tid] = v;
  __syncthreads();
  for (int off = 1; off < 256; off <<= 1) {
    int t = (tid >= off) ? sm[tid - off] : 0;
    __syncthreads();
    sm[tid] += t;
    __syncthreads();
  }
  if (i < n) indptr[i] = sm[tid] - v;
  if (tid == 255) bsum[blockIdx.x] = sm[255];
}

// ---------- launch 4: scan2+scan3 merged (each block reduces its own prefix) ----------
__global__ void k_scan23(int* indptr, const int* bsum, int n, int nb) {
  __shared__ int sm[256];
  int b = blockIdx.x;
  int tid = threadIdx.x;
  sm[tid] = (tid < nb && tid < b) ? bsum[tid] : 0;
  __syncthreads();
  for (int off = 128; off; off >>= 1) {
    if (tid < off) sm[tid] += sm[tid + off];
    __syncthreads();
  }
  int S = sm[0];
  int i = b * 256 + tid;
  if (i < n) indptr[i] += S;
  else if (i == n) indptr[n] = NE;       // grand total is known
}

// ---------- GEMM body (shared by fused L1 and standalone L2-L4) ----------
template <int NOUT, int K>
__device__ __forceinline__ void gemm_body(
    int bid,
    const unsigned short* __restrict__ h0, const unsigned short* __restrict__ h1,
    const unsigned short* __restrict__ h2,
    const unsigned short* __restrict__ Wtb,
    const float* __restrict__ cvec, const float* __restrict__ dinv,
    unsigned short* __restrict__ hb) {
  constexpr int KS = K / 32;
  constexpr int NT = NOUT / 16;
  int tid = threadIdx.x;
  int wv = tid >> 6, lane = tid & 63;
  int row0 = bid * 64 + wv * 16;
  int l15 = lane & 15;
  int kq = lane >> 4;
  int arow = row0 + l15;
  bool inb = arow < NN;

  bf16x8 afrag[KS];
#pragma unroll
  for (int ks = 0; ks < KS; ++ks) {
    int kg = ks * 32 + kq * 8;
    const unsigned short* src = (kg >> 7) == 0 ? h0 : ((kg >> 7) == 1 ? h1 : h2);
    ushort8 u = (ushort8)0;
    if (inb) u = *reinterpret_cast<const ushort8*>(src + (size_t)arow * 128 + (kg & 127));
    afrag[ks] = __builtin_bit_cast(bf16x8, u);
  }

  f32x4 acc[NT];
#pragma unroll
  for (int nt = 0; nt < NT; ++nt) acc[nt] = (f32x4)0.f;

#pragma unroll
  for (int nt = 0; nt < NT; ++nt) {
    const unsigned short* wrow = Wtb + (size_t)(nt * 16 + l15) * K + kq * 8;
#pragma unroll
    for (int ks = 0; ks < KS; ++ks) {
      ushort8 u = *reinterpret_cast<const ushort8*>(wrow + ks * 32);
      acc[nt] = __builtin_amdgcn_mfma_f32_16x16x32_bf16(
          afrag[ks], __builtin_bit_cast(bf16x8, u), acc[nt], 0, 0, 0);
    }
  }

  int orow0 = row0 + kq * 4;
  float dv[4];
  bool ob[4];
#pragma unroll
  for (int r = 0; r < 4; ++r) {
    int orow = orow0 + r;
    ob[r] = orow < NN;
    dv[r] = ob[r] ? dinv[orow] : 0.f;
  }
#pragma unroll
  for (int nt = 0; nt < NT; ++nt) {
    int col = nt * 16 + l15;
    float cv = cvec[col];
#pragma unroll
    for (int r = 0; r < 4; ++r) {
      if (ob[r])
        hb[(size_t)(orow0 + r) * NOUT + col] = f2bf_bits(dv[r] * (acc[nt][r] + cv));
    }
  }
}

// ---------- launch 5: fill || GEMM-L1 (independent; fill hides GEMM) ----------
__global__ __launch_bounds__(256) void k_fill_gemm1(
    const void* ei, const int* __restrict__ rank, const int* __restrict__ indptr,
    const int* __restrict__ cnt8, int* __restrict__ srcs,
    const unsigned short* __restrict__ h0b, const unsigned short* __restrict__ h0d,
    const unsigned short* __restrict__ Wtb, const float* __restrict__ cvec,
    const float* __restrict__ dinv, unsigned short* __restrict__ hb,
    const int* __restrict__ flags) {
  int bid = blockIdx.x;
  if (bid < GE) {                       // --- atomic-free scatter fill ---
    int e = bid * 256 + threadIdx.x;
    if (e >= NE) return;
    int r, c;
    if (flags[1]) {
      const long long* p = (const long long*)ei;
      r = (int)p[e];
      c = (int)p[NE + e];
    } else {
      const int* p = (const int*)ei;
      r = p[e];
      c = p[NE + e];
    }
    int rk = rank[e];
    int sh = (unsigned int)rk >> 27;
    srcs[indptr[c] + cnt8[sh * NN + c] + (rk & 0x07FFFFFF)] = r;
    return;
  }
  const unsigned short* h0 = (flags[0] && h0d) ? h0d : h0b;
  gemm_body<128, 128>(bid - GE, h0, nullptr, nullptr, Wtb, cvec, dinv, hb);
}

// ---------- standalone GEMM (L2-L4) ----------
template <int NOUT, int K>
__global__ __launch_bounds__(256) void k_gemm_mfma(
    const unsigned short* __restrict__ h0b, const unsigned short* __restrict__ h1b,
    const unsigned short* __restrict__ h2b,
    const unsigned short* __restrict__ h0d, const unsigned short* __restrict__ h1d,
    const unsigned short* __restrict__ h2d,
    const unsigned short* __restrict__ Wtb,
    const float* __restrict__ cvec, const float* __restrict__ dinv,
    unsigned short* __restrict__ hb, const int* __restrict__ flags) {
  int isbf = flags[0];
  const unsigned short* h0 = (isbf && h0d) ? h0d : h0b;
  const unsigned short* h1 = (isbf && h1d) ? h1d : h1b;
  const unsigned short* h2 = (isbf && h2d) ? h2d : h2b;
  gemm_body<NOUT, K>(blockIdx.x, h0, h1, h2, Wtb, cvec, dinv, hb);
}

// ---------- aggregation (128-wide): one WAVE per node (R8 layout, measured best) ----
template <bool RELU>
__global__ __launch_bounds__(256) void k_agg128(
    const unsigned short* __restrict__ hb, const int* __restrict__ indptr,
    const int* __restrict__ srcs, const float* __restrict__ dinv,
    const void* __restrict__ bias, void* __restrict__ dout, size_t region_off,
    unsigned short* __restrict__ rb, const int* __restrict__ flags) {
  int gw = __builtin_amdgcn_readfirstlane(blockIdx.x * 4 + (threadIdx.x >> 6));
  int lane = threadIdx.x & 63;
  if (gw >= NN) return;
  int isbf = flags[0];
  int e0 = indptr[gw], e1 = indptr[gw + 1];
  size_t co = (size_t)lane * 2;               // 2 bf16 per lane = 4B
  unsigned int sv = *reinterpret_cast<const unsigned int*>(hb + (size_t)gw * 128 + co);
  float a0 = lo16(sv), a1 = hi16(sv);
  float b0 = 0.f, b1 = 0.f, c0 = 0.f, c1 = 0.f, d0 = 0.f, d1 = 0.f;
  int e = e0;
  for (; e + 7 < e1; e += 8) {                // 8 rows in flight per wave
    int s0 = srcs[e], s1 = srcs[e + 1], s2 = srcs[e + 2], s3 = srcs[e + 3];
    int s4 = srcs[e + 4], s5 = srcs[e + 5], s6 = srcs[e + 6], s7 = srcs[e + 7];
    unsigned int v0 = *reinterpret_cast<const unsigned int*>(hb + (size_t)s0 * 128 + co);
    unsigned int v1 = *reinterpret_cast<const unsigned int*>(hb + (size_t)s1 * 128 + co);
    unsigned int v2 = *reinterpret_cast<const unsigned int*>(hb + (size_t)s2 * 128 + co);
    unsigned int v3 = *reinterpret_cast<const unsigned int*>(hb + (size_t)s3 * 128 + co);
    unsigned int v4 = *reinterpret_cast<const unsigned int*>(hb + (size_t)s4 * 128 + co);
    unsigned int v5 = *reinterpret_cast<const unsigned int*>(hb + (size_t)s5 * 128 + co);
    unsigned int v6 = *reinterpret_cast<const unsigned int*>(hb + (size_t)s6 * 128 + co);
    unsigned int v7 = *reinterpret_cast<const unsigned int*>(hb + (size_t)s7 * 128 + co);
    a0 += lo16(v0); a1 += hi16(v0); b0 += lo16(v1); b1 += hi16(v1);
    c0 += lo16(v2); c1 += hi16(v2); d0 += lo16(v3); d1 += hi16(v3);
    a0 += lo16(v4); a1 += hi16(v4); b0 += lo16(v5); b1 += hi16(v5);
    c0 += lo16(v6); c1 += hi16(v6); d0 += lo16(v7); d1 += hi16(v7);
  }
  for (; e < e1; ++e) {
    int s0 = srcs[e];
    unsigned int v0 = *reinterpret_cast<const unsigned int*>(hb + (size_t)s0 * 128 + co);
    a0 += lo16(v0); a1 += hi16(v0);
  }
  float dv = dinv[gw];
  float o0 = dv * ((a0 + b0) + (c0 + d0)) + loadf(bias, co + 0, isbf);
  float o1 = dv * ((a1 + b1) + (c1 + d1)) + loadf(bias, co + 1, isbf);
  if (RELU) { o0 = fmaxf(o0, 0.f); o1 = fmaxf(o1, 0.f); }
  size_t eo = region_off + (size_t)gw * 128 + co;
  if (isbf) {
    // d_out region doubles as the residual buffer (read by next GEMM)
    unsigned int pk = (unsigned int)f2bf_bits(o0) | ((unsigned int)f2bf_bits(o1) << 16);
    *reinterpret_cast<unsigned int*>((unsigned short*)dout + eo) = pk;
  } else {
    float2 fo; fo.x = o0; fo.y = o1;
    *reinterpret_cast<float2*>((float*)dout + eo) = fo;
    unsigned int pk = (unsigned int)f2bf_bits(o0) | ((unsigned int)f2bf_bits(o1) << 16);
    *reinterpret_cast<unsigned int*>(rb + (size_t)gw * 128 + co) = pk;
  }
}

// ---------- aggregation (64-wide final layer): 32 lanes/node ----------
__global__ __launch_bounds__(256) void k_agg64out(
    const unsigned short* __restrict__ hb, const int* __restrict__ indptr,
    const int* __restrict__ srcs, const float* __restrict__ dinv,
    const void* __restrict__ bias, void* __restrict__ dout,
    const int* __restrict__ flags) {
  int gw = blockIdx.x * 8 + (threadIdx.x >> 5);
  int lane = threadIdx.x & 31;
  if (gw >= NN) return;
  int isbf = flags[0];
  int e0 = indptr[gw], e1 = indptr[gw + 1];
  int e = e0;
  size_t co = (size_t)lane * 2;
  unsigned int sv = *reinterpret_cast<const unsigned int*>(hb + (size_t)gw * 64 + co);
  float a0 = lo16(sv), a1 = hi16(sv);
  float b0 = 0.f, b1 = 0.f, c0 = 0.f, c1 = 0.f, d0 = 0.f, d1 = 0.f;
  for (; e + 3 < e1; e += 4) {
    int sa = srcs[e], sb = srcs[e + 1], sc = srcs[e + 2], sd = srcs[e + 3];
    unsigned int va = *reinterpret_cast<const unsigned int*>(hb + (size_t)sa * 64 + co);
    unsigned int vb = *reinterpret_cast<const unsigned int*>(hb + (size_t)sb * 64 + co);
    unsigned int vc = *reinterpret_cast<const unsigned int*>(hb + (size_t)sc * 64 + co);
    unsigned int vd = *reinterpret_cast<const unsigned int*>(hb + (size_t)sd * 64 + co);
    a0 += lo16(va); a1 += hi16(va); b0 += lo16(vb); b1 += hi16(vb);
    c0 += lo16(vc); c1 += hi16(vc); d0 += lo16(vd); d1 += hi16(vd);
  }
  for (; e < e1; ++e) {
    int sa = srcs[e];
    unsigned int va = *reinterpret_cast<const unsigned int*>(hb + (size_t)sa * 64 + co);
    a0 += lo16(va); a1 += hi16(va);
  }
  float dv = dinv[gw];
  float o0 = dv * ((a0 + b0) + (c0 + d0)) + loadf(bias, co + 0, isbf);
  float o1 = dv * ((a1 + b1) + (c1 + d1)) + loadf(bias, co + 1, isbf);
  size_t eo = (size_t)gw * 64 + co;
  if (isbf) {
    unsigned int pk = (unsigned int)f2bf_bits(o0) | ((unsigned int)f2bf_bits(o1) << 16);
    *reinterpret_cast<unsigned int*>((unsigned short*)dout + eo) = pk;
  } else {
    float2 fo; fo.x = o0; fo.y = o1;
    *reinterpret_cast<float2*>((float*)dout + eo) = fo;
  }
}

extern "C" void kernel_launch(void* const* d_in, const int* in_sizes, int n_in,
                              void* d_out, int out_size, void* d_ws, size_t ws_size,
                              hipStream_t stream) {
  const void* x    = d_in[0];
  const void* ei   = d_in[1];
  const void* W1   = d_in[4];
  const void* b1   = d_in[5];
  const void* Wc0  = d_in[6];
  const void* bc0  = d_in[7];
  const void* Wc1  = d_in[8];
  const void* bc1  = d_in[9];
  const void* Wout = d_in[10];
  const void* bout = d_in[11];
  const void *bn1g = d_in[12], *bn1b = d_in[13], *bn1rm = d_in[14], *bn1rv = d_in[15];
  const void *bc0g = d_in[16], *bc0b = d_in[17], *bc0rm = d_in[18], *bc0rv = d_in[19];
  const void *bc1g = d_in[20], *bc1b = d_in[21], *bc1rm = d_in[22], *bc1rv = d_in[23];
  const void *bn2g = d_in[24], *bn2b = d_in[25], *bn2rm = d_in[26], *bn2rv = d_in[27];
  (void)in_sizes; (void)n_in; (void)out_size; (void)ws_size;

  char* w = (char*)d_ws;
  auto carve = [&](size_t bytes) {
    char* p = w;
    w += (bytes + 255) & ~(size_t)255;
    return p;
  };
  int*   flags  = (int*)  carve(256);
  float* dinv   = (float*)carve(sizeof(float) * NN);
  int*   cnt8   = (int*)  carve(sizeof(int) * 8 * NN);
  int*   indptr = (int*)  carve(sizeof(int) * (NN + 1));
  int*   bsum   = (int*)  carve(sizeof(int) * 256);
  int*   rank   = (int*)  carve(sizeof(int) * NE);
  int*   srcs   = (int*)  carve(sizeof(int) * NE);
  unsigned short* Wtb = (unsigned short*)carve(sizeof(short) * 90112);
  float* cvec   = (float*)carve(sizeof(float) * 448);
  unsigned short* xb  = (unsigned short*)carve(sizeof(short) * (size_t)NN * 128);
  unsigned short* hb  = (unsigned short*)carve(sizeof(short) * (size_t)NN * 128);
  unsigned short* rb0 = (unsigned short*)carve(sizeof(short) * (size_t)NN * 128);
  unsigned short* rb1 = (unsigned short*)carve(sizeof(short) * (size_t)NN * 128);
  unsigned short* rb2 = (unsigned short*)carve(sizeof(short) * (size_t)NN * 128);

  const int gN8 = (8 * NN + 255) / 256;
  const int gG = (NN + 63) / 64;         // 782
  const int gA2 = (NN + 3) / 4;          // agg128: 4 waves/block, 1 node/wave
  const int gA1 = (NN + 7) / 8;          // agg64out: 8 half-waves/block

  // 1: sniff + zero counters
  k_sniff<<<gN8, 256, 0, stream>>>(x, ei, flags, cnt8);
  // 2: edges-count || x-convert || W-prep || c-prep (all flag-dependent only)
  k_fuse_prep<<<GE + GX + GW + GC, 256, 0, stream>>>(
      ei, x, xb, rank, cnt8,
      W1, Wc0, Wc1, Wout, bn1g, bc0g, bc1g, bn2g,
      bn1b, bc0b, bc1b, bn2b, bn1rm, bc0rm, bc1rm, bn2rm,
      bn1rv, bc0rv, bc1rv, bn2rv, Wtb, cvec, flags);
  // 3-4: scan
  k_scan1<<<NB, 256, 0, stream>>>(cnt8, indptr, bsum, dinv, NN);
  k_scan23<<<NB, 256, 0, stream>>>(indptr, bsum, NN, NB);

  const size_t offO  = 0;
  const size_t offR0 = (size_t)NN * 64;
  const size_t offR1 = offR0 + (size_t)NN * 128;
  const size_t offR2 = offR1 + (size_t)NN * 128;
  unsigned short* d0 = (unsigned short*)d_out;   // bf16 view of regions

  // 5: CSR fill || GEMM L1 (independent; GEMM hides under scatter)
  k_fill_gemm1<<<GE + gG, 256, 0, stream>>>(
      ei, rank, indptr, cnt8, srcs,
      xb, (const unsigned short*)x, Wtb + 0, cvec + 0, dinv, hb, flags);
  // 6: agg L1 -> r0
  k_agg128<true><<<gA2, 256, 0, stream>>>(hb, indptr, srcs, dinv, b1, d_out, offR0, rb0, flags);

  // 7-8: L2
  k_gemm_mfma<128, 128><<<gG, 256, 0, stream>>>(
      rb0, nullptr, nullptr, d0 + offR0, nullptr, nullptr, Wtb + 16384, cvec + 128, dinv, hb, flags);
  k_agg128<true><<<gA2, 256, 0, stream>>>(hb, indptr, srcs, dinv, bc0, d_out, offR1, rb1, flags);

  // 9-10: L3
  k_gemm_mfma<128, 256><<<gG, 256, 0, stream>>>(
      rb0, rb1, nullptr, d0 + offR0, d0 + offR1, nullptr, Wtb + 32768, cvec + 256, dinv, hb, flags);
  k_agg128<true><<<gA2, 256, 0, stream>>>(hb, indptr, srcs, dinv, bc1, d_out, offR2, rb2, flags);

  // 11-12: L4
  k_gemm_mfma<64, 384><<<gG, 256, 0, stream>>>(
      rb0, rb1, rb2, d0 + offR0, d0 + offR1, d0 + offR2, Wtb + 65536, cvec + 384, dinv, hb, flags);
  k_agg64out<<<gA1, 256, 0, stream>>>(hb, indptr, srcs, dinv, bout, d_out, flags);
}